// Round 2
// baseline (4378.137 us; speedup 1.0000x reference)
//
#include <hip/hip_runtime.h>
#include <stdint.h>

// ---------------- dims ----------------
constexpr int L = 2, Bb = 2, S = 1024, H = 768, NHd = 12, HD = 64;
constexpr int E = 8, F = 3072, V = 50257;
constexpr int NTOK = Bb * S;        // 2048
constexpr int NSLOT = NTOK * 2;     // 4096 (top-2)
constexpr float EPSLN = 1e-5f;

typedef __attribute__((ext_vector_type(4))) float f32x4;
typedef __attribute__((ext_vector_type(8))) short s16x8;

#define DEVI __device__ __forceinline__

DEVI float bf2f(short u) {
  union { float f; uint32_t i; } c; c.i = ((uint32_t)(uint16_t)u) << 16; return c.f;
}
DEVI short f2bf(float f) {
  union { float f; uint32_t i; } c; c.f = f;
  uint32_t x = c.i;
  uint32_t r = (x + 0x7fffu + ((x >> 16) & 1u)) >> 16;  // RNE
  return (short)r;
}

DEVI void gload16(const void* g, void* l) {
  __builtin_amdgcn_global_load_lds(g, l, 16, 0, 0);
}

// ---------------- small kernels ----------------
__global__ void k_f32_to_bf16(const float* __restrict__ in, short* __restrict__ out, long n4) {
  long i = (long)blockIdx.x * blockDim.x + threadIdx.x;
  if (i >= n4) return;
  long base = i * 4;
  f32x4 v = *(const f32x4*)(in + base);
  short4 o;
  o.x = f2bf(v.x); o.y = f2bf(v.y); o.z = f2bf(v.z); o.w = f2bf(v.w);
  *(short4*)(out + base) = o;
}

__global__ void k_bqkv(const float* __restrict__ bq, const float* __restrict__ bk,
                       const float* __restrict__ bv, float* __restrict__ bqkv) {
  int i = blockIdx.x * blockDim.x + threadIdx.x;
  if (i >= L * 3 * H) return;
  int l = i / (3 * H), j = i % (3 * H);
  float v = (j < H) ? bq[l * H + j] : (j < 2 * H) ? bk[l * H + j - H] : bv[l * H + j - 2 * H];
  bqkv[i] = v;
}

// concat Wq|Wk|Wv of layer l into [768][2304] ([k][n])
__global__ void k_wcat(const float* __restrict__ Wq, const float* __restrict__ Wk,
                       const float* __restrict__ Wv, float* __restrict__ out) {
  int i = blockIdx.x * blockDim.x + threadIdx.x;  // H*H
  if (i >= H * H) return;
  int k = i / H, n = i % H;
  out[(size_t)k * 3 * H + n] = Wq[i];
  out[(size_t)k * 3 * H + H + n] = Wk[i];
  out[(size_t)k * 3 * H + 2 * H + n] = Wv[i];
}

__global__ void k_ropetab(float* __restrict__ cosT, float* __restrict__ sinT) {
  int i = blockIdx.x * blockDim.x + threadIdx.x;
  if (i >= S * (HD / 2)) return;
  int s = i / 32, d = i % 32;
  float invf = powf(10000.f, -(2.f * d) / (float)HD);
  float ang = (float)s * invf;
  cosT[i] = cosf(ang);
  sinT[i] = sinf(ang);
}

__global__ void k_embed(const int* __restrict__ ids, const float* __restrict__ emb,
                        float* __restrict__ x) {
  int idx = blockIdx.x * blockDim.x + threadIdx.x;  // NTOK*(H/4)
  int row = idx / (H / 4), c4 = idx % (H / 4);
  if (row >= NTOK) return;
  int t = ids[row];
  ((f32x4*)(x + (size_t)row * H))[c4] = ((const f32x4*)(emb + (size_t)t * H))[c4];
}

// ---------------- layernorm (f32 in, f32 or bf16 out) ----------------
template <bool BF>
__global__ void k_layernorm(const float* __restrict__ x, const float* __restrict__ w,
                            const float* __restrict__ b, void* __restrict__ outp) {
  int row = blockIdx.x * (blockDim.x >> 6) + (threadIdx.x >> 6);
  int lane = threadIdx.x & 63;
  if (row >= NTOK) return;
  const float* xr = x + (size_t)row * H;
  float v[12], s = 0.f, s2 = 0.f;
#pragma unroll
  for (int j = 0; j < 12; j++) { float t = xr[lane + j * 64]; v[j] = t; s += t; s2 += t * t; }
#pragma unroll
  for (int off = 32; off; off >>= 1) { s += __shfl_xor(s, off); s2 += __shfl_xor(s2, off); }
  float m = s / (float)H;
  float var = s2 / (float)H - m * m;
  float rs = 1.f / sqrtf(var + EPSLN);
#pragma unroll
  for (int j = 0; j < 12; j++) {
    int c = lane + j * 64;
    float val = (v[j] - m) * rs * w[c] + b[c];
    if (BF) ((short*)outp)[(size_t)row * H + c] = f2bf(val);
    else    ((float*)outp)[(size_t)row * H + c] = val;
  }
}

// ---------------- rope (all f32) ----------------
__global__ void k_rope(const float* __restrict__ qkv, const float* __restrict__ cosT,
                       const float* __restrict__ sinT, float* __restrict__ qf,
                       float* __restrict__ kT, float* __restrict__ vf) {
  int idx = blockIdx.x * blockDim.x + threadIdx.x;  // B*S*NH*32
  if (idx >= Bb * S * NHd * 32) return;
  int d = idx & 31;
  int h = (idx >> 5) % NHd;
  int t = idx / (32 * NHd);  // token = b*S+s
  int s = t % S, b = t / S;
  const float* base = qkv + (size_t)t * (3 * H) + h * HD;
  float c = cosT[s * 32 + d], sn = sinT[s * 32 + d];
  float q1 = base[d], q2 = base[d + 32];
  float k1 = base[H + d], k2 = base[H + d + 32];
  float v1 = base[2 * H + d], v2 = base[2 * H + d + 32];
  size_t z = (size_t)(b * NHd + h);
  size_t qk = (z * S + s) * HD;
  qf[qk + d]      = q1 * c - q2 * sn;
  qf[qk + d + 32] = q2 * c + q1 * sn;
  kT[z * HD * S + (size_t)d * S + s]        = k1 * c - k2 * sn;
  kT[z * HD * S + (size_t)(d + 32) * S + s] = k2 * c + k1 * sn;
  vf[qk + d]      = v1;
  vf[qk + d + 32] = v2;
}

// ---------------- softmax (f32 in place) ----------------
__global__ void k_softmax(float* __restrict__ att) {
  int row = blockIdx.x * (blockDim.x >> 6) + (threadIdx.x >> 6);  // B*NH*S rows
  int lane = threadIdx.x & 63;
  if (row >= Bb * NHd * S) return;
  float* pr = att + (size_t)row * S;
  float v[16], mx = -3e38f;
#pragma unroll
  for (int j = 0; j < 16; j++) { v[j] = pr[lane + j * 64]; mx = fmaxf(mx, v[j]); }
#pragma unroll
  for (int off = 32; off; off >>= 1) mx = fmaxf(mx, __shfl_xor(mx, off));
  float sum = 0.f;
#pragma unroll
  for (int j = 0; j < 16; j++) { v[j] = expf(v[j] - mx); sum += v[j]; }
#pragma unroll
  for (int off = 32; off; off >>= 1) sum += __shfl_xor(sum, off);
  float inv = 1.f / sum;
#pragma unroll
  for (int j = 0; j < 16; j++) pr[lane + j * 64] = v[j] * inv;
}

// ---------------- router (f32 h input -> exact top-2) ----------------
__global__ void k_router(const float* __restrict__ h, const float* __restrict__ Wr,
                         const float* __restrict__ br, float* __restrict__ sel_w,
                         int* __restrict__ sel_e, int* __restrict__ counts) {
  int tok = blockIdx.x * (blockDim.x >> 6) + (threadIdx.x >> 6);
  int lane = threadIdx.x & 63;
  if (tok >= NTOK) return;
  const float* hr = h + (size_t)tok * H;
  float acc[8] = {0, 0, 0, 0, 0, 0, 0, 0};
  for (int i = lane; i < H; i += 64) {
    float hv = hr[i];
    const f32x4* w4 = (const f32x4*)(Wr + (size_t)i * E);
    f32x4 a = w4[0], b = w4[1];
    acc[0] += hv * a.x; acc[1] += hv * a.y; acc[2] += hv * a.z; acc[3] += hv * a.w;
    acc[4] += hv * b.x; acc[5] += hv * b.y; acc[6] += hv * b.z; acc[7] += hv * b.w;
  }
#pragma unroll
  for (int off = 32; off; off >>= 1)
#pragma unroll
    for (int e = 0; e < 8; e++) acc[e] += __shfl_xor(acc[e], off);
  if (lane == 0) {
    float lg[8], m = -3e38f;
#pragma unroll
    for (int e = 0; e < 8; e++) { lg[e] = acc[e] + br[e]; m = fmaxf(m, lg[e]); }
    float sum = 0.f;
#pragma unroll
    for (int e = 0; e < 8; e++) { lg[e] = expf(lg[e] - m); sum += lg[e]; }
    float inv = 1.f / sum;
#pragma unroll
    for (int e = 0; e < 8; e++) lg[e] *= inv;
    int i1 = 0;
#pragma unroll
    for (int e = 1; e < 8; e++) if (lg[e] > lg[i1]) i1 = e;
    int i2 = (i1 == 0) ? 1 : 0;
#pragma unroll
    for (int e = 0; e < 8; e++) if (e != i1 && lg[e] > lg[i2]) i2 = e;
    float p1 = lg[i1], p2 = lg[i2];
    float ws = p1 + p2 + 1e-9f;
    sel_e[tok * 2] = i1; sel_e[tok * 2 + 1] = i2;
    sel_w[tok * 2] = p1 / ws; sel_w[tok * 2 + 1] = p2 / ws;
    atomicAdd(counts + i1, 1);
    atomicAdd(counts + i2, 1);
  }
}

__global__ void k_offsets(const int* __restrict__ counts, int* __restrict__ offs) {
  if (threadIdx.x == 0) {
    int a = 0;
    for (int e = 0; e < E; e++) { offs[e] = a; a += counts[e]; }
    offs[E] = a;
  }
}

__global__ void k_scatter(const int* __restrict__ sel_e, const int* __restrict__ offs,
                          int* __restrict__ cursor, int* __restrict__ tok_list,
                          int* __restrict__ slot_of) {
  int tok = blockIdx.x * blockDim.x + threadIdx.x;
  if (tok >= NTOK) return;
  for (int k = 0; k < 2; k++) {
    int e = sel_e[tok * 2 + k];
    int pos = atomicAdd(cursor + e, 1);
    int g = offs[e] + pos;
    tok_list[g] = tok;
    slot_of[tok * 2 + k] = g;
  }
}

__global__ void k_combine(const float* __restrict__ oe, const float* __restrict__ sel_w,
                          const int* __restrict__ slot_of, float* __restrict__ x) {
  int idx = blockIdx.x * blockDim.x + threadIdx.x;  // NTOK*(H/4)
  if (idx >= NTOK * (H / 4)) return;
  int tok = idx / (H / 4), c4 = idx % (H / 4);
  float w0 = sel_w[tok * 2], w1 = sel_w[tok * 2 + 1];
  int s0 = slot_of[tok * 2], s1 = slot_of[tok * 2 + 1];
  f32x4 a = ((const f32x4*)(oe + (size_t)s0 * H))[c4];
  f32x4 b = ((const f32x4*)(oe + (size_t)s1 * H))[c4];
  f32x4* xp = (f32x4*)(x + (size_t)tok * H) + c4;
  *xp = *xp + w0 * a + w1 * b;
}

// ---------------- f32 SGEMM ----------------
// C[z][m][n] = sum_k A[z][row(m)][k] * B[z][k][n]    (all f32)
// MODE 0: +bias(opt)  1: res+acc+bias  2: acc*alpha + causal  4: gelu(acc+bias)
// 128x128 tile, 256 threads, 8x8 micro, K-step 8. K must be a multiple of 8.
template <int MODE, bool GATHER>
__global__ __launch_bounds__(256) void k_sgemm(
    const float* __restrict__ A, long sAz, int lda,
    const float* __restrict__ B, long sBz, int ldb,
    float* __restrict__ C, int zdiv, long sChi, long sClo, int ldc,
    const float* __restrict__ bias, long sBias, const float* __restrict__ res,
    int M, int N, int K,
    const int* __restrict__ cnts, const int* __restrict__ offs,
    const int* __restrict__ gidx, float alpha) {
  const int z = blockIdx.z;
  const int Meff = cnts ? cnts[z] : M;
  const int tm = blockIdx.y;
  if (tm * 128 >= Meff) return;
  const int tn = blockIdx.x;
  const int row_base = offs ? offs[z] : 0;

  __shared__ float As[8][128];
  __shared__ float Bs[8][132];

  const int tid = threadIdx.x;

  // A staging: thread t -> row tm*128 + (t>>1), k-quad (t&1)*4
  int arow = tm * 128 + (tid >> 1);
  if (arow > Meff - 1) arow = Meff - 1;
  int agr = row_base + arow;
  if (GATHER) agr = gidx[agr];
  const int akk = (tid & 1) * 4;
  const int am = tid >> 1;
  const float* aP = A + (size_t)z * sAz + (size_t)agr * lda + akk;

  // B staging: thread t -> k-row (t>>5), col-quad (t&31)*4
  const int bkk = tid >> 5;
  const int bn4 = (tid & 31) * 4;
  const float* bP = B + (size_t)z * sBz + (size_t)bkk * ldb + tn * 128 + bn4;
  const bool fullN = (tn * 128 + 128 <= N);
  const int cb = tn * 128 + bn4;

  float acc[8][8] = {};
  const int ty = tid >> 4, tx = tid & 15;

  for (int k0 = 0; k0 < K; k0 += 8) {
    float4 av = *(const float4*)aP;
    float4 bv;
    if (fullN) {
      bv = *(const float4*)bP;
    } else {
      bv.x = (cb + 0 < N) ? bP[0] : 0.f;
      bv.y = (cb + 1 < N) ? bP[1] : 0.f;
      bv.z = (cb + 2 < N) ? bP[2] : 0.f;
      bv.w = (cb + 3 < N) ? bP[3] : 0.f;
    }
    __syncthreads();
    As[akk + 0][am] = av.x; As[akk + 1][am] = av.y;
    As[akk + 2][am] = av.z; As[akk + 3][am] = av.w;
    *(float4*)&Bs[bkk][bn4] = bv;
    __syncthreads();
#pragma unroll
    for (int kk = 0; kk < 8; ++kk) {
      float a8[8], b8[8];
#pragma unroll
      for (int i = 0; i < 8; ++i) a8[i] = As[kk][ty * 8 + i];
#pragma unroll
      for (int j = 0; j < 8; ++j) b8[j] = Bs[kk][tx * 8 + j];
#pragma unroll
      for (int i = 0; i < 8; ++i)
#pragma unroll
        for (int j = 0; j < 8; ++j) acc[i][j] = fmaf(a8[i], b8[j], acc[i][j]);
    }
    aP += 8;
    bP += (size_t)8 * ldb;
  }

  const long out_off = (long)(z / zdiv) * sChi + (long)(z % zdiv) * sClo;
  const float* bz = bias ? bias + (size_t)z * sBias : nullptr;
#pragma unroll
  for (int i = 0; i < 8; ++i) {
    const int lrow = tm * 128 + ty * 8 + i;
    if (lrow >= Meff) continue;
    const long orow = row_base + lrow;
    const long rbase = out_off + orow * (long)ldc;
#pragma unroll
    for (int j = 0; j < 8; ++j) {
      const int gcol = tn * 128 + tx * 8 + j;
      if (gcol >= N) continue;
      const long idx = rbase + gcol;
      float v = acc[i][j];
      if (MODE == 0) {
        C[idx] = v + (bz ? bz[gcol] : 0.f);
      } else if (MODE == 1) {
        C[idx] = res[idx] + v + bz[gcol];
      } else if (MODE == 2) {
        C[idx] = v * alpha + ((gcol > lrow) ? -1e9f : 0.f);
      } else if (MODE == 4) {
        float g = v + bz[gcol];
        C[idx] = 0.5f * g * (1.f + erff(g * 0.70710678118f));
      }
    }
  }
}

template <int MODE, bool GATHER>
static void sgemm(hipStream_t st, const float* A, long sAz, int lda, const float* B, long sBz,
                  int ldb, float* C, int zdiv, long sChi, long sClo, int ldc, const float* bias,
                  long sBias, const float* res, int M, int N, int K, int nz, const int* cnts,
                  const int* offs_, const int* gat, float alpha) {
  dim3 g((N + 127) / 128, (M + 127) / 128, nz);
  k_sgemm<MODE, GATHER><<<g, 256, 0, st>>>(A, sAz, lda, B, sBz, ldb, C, zdiv, sChi, sClo, ldc,
                                           bias, sBias, res, M, N, K, cnts, offs_, gat, alpha);
}

// ---------------- bf16 MFMA GEMM (logits only) ----------------
// C[m][n] = sum_k A[m][k] * Bt[n][k]   (A,Bt bf16 row-major; C f32)
__global__ __launch_bounds__(256, 2) void k_gemm_bf16(
    const short* __restrict__ A, int lda, const short* __restrict__ Bt, int ldb,
    float* __restrict__ Cp, int ldc, int M, int N, int K) {
  const int tm = blockIdx.y;
  const int tn = blockIdx.x;

  __shared__ short Abuf[128 * 32];
  __shared__ short Bbuf[128 * 32];

  const int tid = threadIdx.x;
  const int lane = tid & 63;
  const int w = tid >> 6;

  const short* aSrc[2];
  const short* bSrc[2];
#pragma unroll
  for (int i = 0; i < 2; ++i) {
    const int srow = i * 64 + (tid >> 2);
    const int kb = (tid & 3) ^ (srow & 3);  // XOR swizzle (both-sides involution)
    int lrow = tm * 128 + srow;
    if (lrow > M - 1) lrow = M - 1;
    aSrc[i] = A + (size_t)lrow * lda + kb * 8;
    int bcol = tn * 128 + srow;
    if (bcol > N - 1) bcol = N - 1;
    bSrc[i] = Bt + (size_t)bcol * ldb + kb * 8;
  }

  f32x4 acc[4][4];
#pragma unroll
  for (int a = 0; a < 4; ++a)
#pragma unroll
    for (int b = 0; b < 4; ++b) acc[a][b] = {0.f, 0.f, 0.f, 0.f};

  const int wr = (w >> 1) * 64;
  const int wc = (w & 1) * 64;
  const int r16 = lane & 15;
  const int kb4 = lane >> 4;
  const int swz = (kb4 ^ (r16 & 3)) * 8;
  int aoff[4], boff[4];
#pragma unroll
  for (int i = 0; i < 4; ++i) {
    aoff[i] = (wr + i * 16 + r16) * 32 + swz;
    boff[i] = (wc + i * 16 + r16) * 32 + swz;
  }
  char* const ldsA0 = (char*)Abuf + w * 1024;
  char* const ldsA1 = (char*)Abuf + 4096 + w * 1024;
  char* const ldsB0 = (char*)Bbuf + w * 1024;
  char* const ldsB1 = (char*)Bbuf + 4096 + w * 1024;

  for (int k0 = 0; k0 < K; k0 += 32) {
    gload16(aSrc[0], ldsA0);
    gload16(aSrc[1], ldsA1);
    gload16(bSrc[0], ldsB0);
    gload16(bSrc[1], ldsB1);
    aSrc[0] += 32; aSrc[1] += 32; bSrc[0] += 32; bSrc[1] += 32;
    __syncthreads();
    s16x8 af[4], bf[4];
#pragma unroll
    for (int i = 0; i < 4; ++i) {
      af[i] = *(const s16x8*)(Abuf + aoff[i]);
      bf[i] = *(const s16x8*)(Bbuf + boff[i]);
    }
#pragma unroll
    for (int mi = 0; mi < 4; ++mi)
#pragma unroll
      for (int ni = 0; ni < 4; ++ni)
        acc[mi][ni] =
            __builtin_amdgcn_mfma_f32_16x16x32_bf16(af[mi], bf[ni], acc[mi][ni], 0, 0, 0);
    __syncthreads();
  }

  const int q4 = lane >> 4;
#pragma unroll
  for (int ni = 0; ni < 4; ++ni) {
    const int gcol = tn * 128 + wc + ni * 16 + r16;
    if (gcol >= N) continue;
#pragma unroll
    for (int mi = 0; mi < 4; ++mi) {
#pragma unroll
      for (int j = 0; j < 4; ++j) {
        const int lrow = tm * 128 + wr + mi * 16 + q4 * 4 + j;
        if (lrow >= M) continue;
        Cp[(long)lrow * ldc + gcol] = acc[mi][ni][j];
      }
    }
  }
}

// ---------------- launch ----------------
extern "C" void kernel_launch(void* const* d_in, const int* in_sizes, int n_in, void* d_out,
                              int out_size, void* d_ws, size_t ws_size, hipStream_t stream) {
  (void)in_sizes; (void)n_in; (void)out_size; (void)ws_size;
  const int*   ids  = (const int*)d_in[0];
  const float* emb  = (const float*)d_in[1];
  const float* ln1w = (const float*)d_in[2];
  const float* ln1b = (const float*)d_in[3];
  const float* ln2w = (const float*)d_in[4];
  const float* ln2b = (const float*)d_in[5];
  const float* lnfw = (const float*)d_in[6];
  const float* lnfb = (const float*)d_in[7];
  const float* Wq = (const float*)d_in[8];
  const float* bq = (const float*)d_in[9];
  const float* Wk = (const float*)d_in[10];
  const float* bk = (const float*)d_in[11];
  const float* Wv = (const float*)d_in[12];
  const float* bv = (const float*)d_in[13];
  const float* Wo = (const float*)d_in[14];
  const float* bo = (const float*)d_in[15];
  const float* Wr = (const float*)d_in[16];
  const float* br = (const float*)d_in[17];
  const float* W1 = (const float*)d_in[18];
  const float* b1 = (const float*)d_in[19];
  const float* W2 = (const float*)d_in[20];
  const float* b2 = (const float*)d_in[21];
  float* out = (float*)d_out;

  char* p = (char*)d_ws;
  auto alloc = [&](size_t bytes) {
    char* r = p;
    p += (bytes + 255) & ~(size_t)255;
    return r;
  };
  short* embB = (short*)alloc((size_t)V * H * 2);          // 77.2 MB
  float* bqkv = (float*)alloc((size_t)L * 3 * H * 4);
  float* Wcat = (float*)alloc((size_t)3 * H * H * 4);      // 7.1 MB (per-layer reuse)
  float* cosT = (float*)alloc((size_t)S * 32 * 4);
  float* sinT = (float*)alloc((size_t)S * 32 * 4);
  float* x    = (float*)alloc((size_t)NTOK * H * 4);
  float* hbuf = (float*)alloc((size_t)NTOK * H * 4);
  float* qf   = (float*)alloc((size_t)NTOK * H * 4);
  float* kT   = (float*)alloc((size_t)NTOK * H * 4);
  float* vf   = (float*)alloc((size_t)NTOK * H * 4);
  float* o    = (float*)alloc((size_t)NTOK * H * 4);
  short* xb   = (short*)alloc((size_t)NTOK * H * 2);
  // union region: qkvl (18.9MB) -> att f32 (100.7MB) -> act(50.3)+oe(12.6)
  char* uni = alloc((size_t)Bb * NHd * S * S * 4);         // 100.7 MB
  float* qkvl = (float*)uni;
  float* att  = (float*)uni;
  float* act  = (float*)uni;
  float* oe   = (float*)(uni + (size_t)NSLOT * F * 4);
  int* counts  = (int*)alloc(2 * E * 4);
  int* cursor  = counts + E;
  int* offs    = (int*)alloc((E + 1) * 4);
  int* sel_e   = (int*)alloc((size_t)NTOK * 2 * 4);
  float* sel_w = (float*)alloc((size_t)NTOK * 2 * 4);
  int* slot_of = (int*)alloc((size_t)NTOK * 2 * 4);
  int* tok_lst = (int*)alloc((size_t)NSLOT * 4);

  // ---- prologue ----
  long nEmb4 = (long)V * H / 4;
  k_f32_to_bf16<<<(nEmb4 + 255) / 256, 256, 0, stream>>>(emb, embB, nEmb4);
  k_bqkv<<<(L * 3 * H + 255) / 256, 256, 0, stream>>>(bq, bk, bv, bqkv);
  k_ropetab<<<(S * 32 + 255) / 256, 256, 0, stream>>>(cosT, sinT);
  k_embed<<<(NTOK * (H / 4) + 255) / 256, 256, 0, stream>>>(ids, emb, x);

  for (int l = 0; l < L; l++) {
    // --- attention ---
    k_layernorm<false><<<NTOK / 4, 256, 0, stream>>>(x, ln1w + l * H, ln1b + l * H, hbuf);
    k_wcat<<<(H * H + 255) / 256, 256, 0, stream>>>(Wq + (size_t)l * H * H,
                                                    Wk + (size_t)l * H * H,
                                                    Wv + (size_t)l * H * H, Wcat);
    sgemm<0, false>(stream, hbuf, 0, H, Wcat, 0, 3 * H, qkvl, 1, 0, 0, 3 * H,
                    bqkv + l * 3 * H, 0, nullptr, NTOK, 3 * H, H, 1, nullptr, nullptr, nullptr,
                    1.f);
    k_rope<<<(Bb * S * NHd * 32 + 255) / 256, 256, 0, stream>>>(qkvl, cosT, sinT, qf, kT, vf);
    sgemm<2, false>(stream, qf, (long)S * HD, HD, kT, (long)HD * S, S, att, 1, (long)S * S, 0,
                    S, nullptr, 0, nullptr, S, S, HD, Bb * NHd, nullptr, nullptr, nullptr,
                    0.125f);
    k_softmax<<<(Bb * NHd * S) / 4, 256, 0, stream>>>(att);
    sgemm<0, false>(stream, att, (long)S * S, S, vf, (long)S * HD, HD, o, NHd, (long)S * H, HD,
                    H, nullptr, 0, nullptr, S, HD, S, Bb * NHd, nullptr, nullptr, nullptr, 1.f);
    sgemm<1, false>(stream, o, 0, H, Wo + (size_t)l * H * H, 0, H, x, 1, 0, 0, H, bo + l * H, 0,
                    x, NTOK, H, H, 1, nullptr, nullptr, nullptr, 1.f);

    // --- MoE ---
    k_layernorm<false><<<NTOK / 4, 256, 0, stream>>>(x, ln2w + l * H, ln2b + l * H, hbuf);
    hipMemsetAsync(counts, 0, 2 * E * sizeof(int), stream);
    k_router<<<NTOK / 4, 256, 0, stream>>>(hbuf, Wr + (size_t)l * H * E, br + l * E, sel_w,
                                           sel_e, counts);
    k_offsets<<<1, 64, 0, stream>>>(counts, offs);
    k_scatter<<<(NTOK + 255) / 256, 256, 0, stream>>>(sel_e, offs, cursor, tok_lst, slot_of);
    sgemm<4, true>(stream, hbuf, 0, H, W1 + (size_t)l * E * H * F, (long)H * F, F, act, 1, 0, 0,
                   F, b1 + (size_t)l * E * F, F, nullptr, NSLOT, F, H, E, counts, offs, tok_lst,
                   1.f);
    sgemm<0, false>(stream, act, 0, F, W2 + (size_t)l * E * F * H, (long)F * H, H, oe, 1, 0, 0,
                    H, b2 + (size_t)l * E * H, H, nullptr, NSLOT, H, F, E, counts, offs,
                    nullptr, 1.f);
    k_combine<<<(NTOK * (H / 4) + 255) / 256, 256, 0, stream>>>(oe, sel_w, slot_of, x);
  }

  // --- final LN + tied logits (bf16 MFMA; downstream of all routers) ---
  k_layernorm<true><<<NTOK / 4, 256, 0, stream>>>(x, lnfw, lnfb, xb);
  dim3 lg((V + 127) / 128, (NTOK + 127) / 128, 1);
  k_gemm_bf16<<<lg, 256, 0, stream>>>(xb, H, embB, H, out, V, NTOK, V, H);
}

// Round 3
// 2321.659 us; speedup vs baseline: 1.8858x; 1.8858x over previous
//
#include <hip/hip_runtime.h>
#include <stdint.h>

// ---------------- dims ----------------
constexpr int L = 2, Bb = 2, S = 1024, H = 768, NHd = 12, HD = 64;
constexpr int E = 8, F = 3072, V = 50257;
constexpr int NTOK = Bb * S;        // 2048
constexpr int NSLOT = NTOK * 2;     // 4096 (top-2)
constexpr float EPSLN = 1e-5f;

typedef __attribute__((ext_vector_type(4))) float f32x4;
typedef __attribute__((ext_vector_type(8))) short s16x8;

#define DEVI __device__ __forceinline__

DEVI float bf2f(short u) {
  union { float f; uint32_t i; } c; c.i = ((uint32_t)(uint16_t)u) << 16; return c.f;
}
DEVI short f2bf(float f) {
  union { float f; uint32_t i; } c; c.f = f;
  uint32_t x = c.i;
  uint32_t r = (x + 0x7fffu + ((x >> 16) & 1u)) >> 16;  // RNE
  return (short)r;
}

DEVI void gload16(const void* g, void* l) {
  __builtin_amdgcn_global_load_lds(g, l, 16, 0, 0);
}

// ---------------- small kernels ----------------
__global__ void k_f32_to_bf16(const float* __restrict__ in, short* __restrict__ out, long n4) {
  long i = (long)blockIdx.x * blockDim.x + threadIdx.x;
  if (i >= n4) return;
  long base = i * 4;
  f32x4 v = *(const f32x4*)(in + base);
  short4 o;
  o.x = f2bf(v.x); o.y = f2bf(v.y); o.z = f2bf(v.z); o.w = f2bf(v.w);
  *(short4*)(out + base) = o;
}

// in  f32 [batch][R][C]  ->  out bf16 [batch][C][R]
__global__ void k_transpose_bf16(const float* __restrict__ in, short* __restrict__ out,
                                 int R, int C, long inBS, long outBS) {
  __shared__ float tile[32][33];
  const float* src = in + (size_t)blockIdx.z * inBS;
  short* dst = out + (size_t)blockIdx.z * outBS;
  int r0 = blockIdx.y * 32, c0 = blockIdx.x * 32;
  int tx = threadIdx.x, ty = threadIdx.y;
#pragma unroll
  for (int i = 0; i < 32; i += 8) {
    int r = r0 + ty + i, c = c0 + tx;
    if (r < R && c < C) tile[ty + i][tx] = src[(size_t)r * C + c];
  }
  __syncthreads();
#pragma unroll
  for (int i = 0; i < 32; i += 8) {
    int c = c0 + ty + i, r = r0 + tx;
    if (r < R && c < C) dst[(size_t)c * R + r] = f2bf(tile[tx][ty + i]);
  }
}

__global__ void k_bqkv(const float* __restrict__ bq, const float* __restrict__ bk,
                       const float* __restrict__ bv, float* __restrict__ bqkv) {
  int i = blockIdx.x * blockDim.x + threadIdx.x;
  if (i >= L * 3 * H) return;
  int l = i / (3 * H), j = i % (3 * H);
  float v = (j < H) ? bq[l * H + j] : (j < 2 * H) ? bk[l * H + j - H] : bv[l * H + j - 2 * H];
  bqkv[i] = v;
}

// concat Wq|Wk|Wv of layer l into [768][2304] ([k][n])
__global__ void k_wcat(const float* __restrict__ Wq, const float* __restrict__ Wk,
                       const float* __restrict__ Wv, float* __restrict__ out) {
  int i = blockIdx.x * blockDim.x + threadIdx.x;  // H*H
  if (i >= H * H) return;
  int k = i / H, n = i % H;
  out[(size_t)k * 3 * H + n] = Wq[i];
  out[(size_t)k * 3 * H + H + n] = Wk[i];
  out[(size_t)k * 3 * H + 2 * H + n] = Wv[i];
}

__global__ void k_ropetab(float* __restrict__ cosT, float* __restrict__ sinT) {
  int i = blockIdx.x * blockDim.x + threadIdx.x;
  if (i >= S * (HD / 2)) return;
  int s = i / 32, d = i % 32;
  float invf = powf(10000.f, -(2.f * d) / (float)HD);
  float ang = (float)s * invf;
  cosT[i] = cosf(ang);
  sinT[i] = sinf(ang);
}

__global__ void k_embed(const int* __restrict__ ids, const float* __restrict__ emb,
                        float* __restrict__ x) {
  int idx = blockIdx.x * blockDim.x + threadIdx.x;  // NTOK*(H/4)
  int row = idx / (H / 4), c4 = idx % (H / 4);
  if (row >= NTOK) return;
  int t = ids[row];
  ((f32x4*)(x + (size_t)row * H))[c4] = ((const f32x4*)(emb + (size_t)t * H))[c4];
}

// ---------------- layernorm (f32 in, f32 or bf16 out) ----------------
template <bool BF>
__global__ void k_layernorm(const float* __restrict__ x, const float* __restrict__ w,
                            const float* __restrict__ b, void* __restrict__ outp) {
  int row = blockIdx.x * (blockDim.x >> 6) + (threadIdx.x >> 6);
  int lane = threadIdx.x & 63;
  if (row >= NTOK) return;
  const float* xr = x + (size_t)row * H;
  float v[12], s = 0.f, s2 = 0.f;
#pragma unroll
  for (int j = 0; j < 12; j++) { float t = xr[lane + j * 64]; v[j] = t; s += t; s2 += t * t; }
#pragma unroll
  for (int off = 32; off; off >>= 1) { s += __shfl_xor(s, off); s2 += __shfl_xor(s2, off); }
  float m = s / (float)H;
  float var = s2 / (float)H - m * m;
  float rs = 1.f / sqrtf(var + EPSLN);
#pragma unroll
  for (int j = 0; j < 12; j++) {
    int c = lane + j * 64;
    float val = (v[j] - m) * rs * w[c] + b[c];
    if (BF) ((short*)outp)[(size_t)row * H + c] = f2bf(val);
    else    ((float*)outp)[(size_t)row * H + c] = val;
  }
}

// ---------------- rope (all f32) ----------------
__global__ void k_rope(const float* __restrict__ qkv, const float* __restrict__ cosT,
                       const float* __restrict__ sinT, float* __restrict__ qf,
                       float* __restrict__ kT, float* __restrict__ vf) {
  int idx = blockIdx.x * blockDim.x + threadIdx.x;  // B*S*NH*32
  if (idx >= Bb * S * NHd * 32) return;
  int d = idx & 31;
  int h = (idx >> 5) % NHd;
  int t = idx / (32 * NHd);  // token = b*S+s
  int s = t % S, b = t / S;
  const float* base = qkv + (size_t)t * (3 * H) + h * HD;
  float c = cosT[s * 32 + d], sn = sinT[s * 32 + d];
  float q1 = base[d], q2 = base[d + 32];
  float k1 = base[H + d], k2 = base[H + d + 32];
  float v1 = base[2 * H + d], v2 = base[2 * H + d + 32];
  size_t z = (size_t)(b * NHd + h);
  size_t qk = (z * S + s) * HD;
  qf[qk + d]      = q1 * c - q2 * sn;
  qf[qk + d + 32] = q2 * c + q1 * sn;
  kT[z * HD * S + (size_t)d * S + s]        = k1 * c - k2 * sn;
  kT[z * HD * S + (size_t)(d + 32) * S + s] = k2 * c + k1 * sn;
  vf[qk + d]      = v1;
  vf[qk + d + 32] = v2;
}

// ---------------- softmax (f32 in place) ----------------
__global__ void k_softmax(float* __restrict__ att) {
  int row = blockIdx.x * (blockDim.x >> 6) + (threadIdx.x >> 6);  // B*NH*S rows
  int lane = threadIdx.x & 63;
  if (row >= Bb * NHd * S) return;
  float* pr = att + (size_t)row * S;
  float v[16], mx = -3e38f;
#pragma unroll
  for (int j = 0; j < 16; j++) { v[j] = pr[lane + j * 64]; mx = fmaxf(mx, v[j]); }
#pragma unroll
  for (int off = 32; off; off >>= 1) mx = fmaxf(mx, __shfl_xor(mx, off));
  float sum = 0.f;
#pragma unroll
  for (int j = 0; j < 16; j++) { v[j] = expf(v[j] - mx); sum += v[j]; }
#pragma unroll
  for (int off = 32; off; off >>= 1) sum += __shfl_xor(sum, off);
  float inv = 1.f / sum;
#pragma unroll
  for (int j = 0; j < 16; j++) pr[lane + j * 64] = v[j] * inv;
}

// ---------------- router (f32 h input -> exact top-2) ----------------
__global__ void k_router(const float* __restrict__ h, const float* __restrict__ Wr,
                         const float* __restrict__ br, float* __restrict__ sel_w,
                         int* __restrict__ sel_e, int* __restrict__ counts) {
  int tok = blockIdx.x * (blockDim.x >> 6) + (threadIdx.x >> 6);
  int lane = threadIdx.x & 63;
  if (tok >= NTOK) return;
  const float* hr = h + (size_t)tok * H;
  float acc[8] = {0, 0, 0, 0, 0, 0, 0, 0};
  for (int i = lane; i < H; i += 64) {
    float hv = hr[i];
    const f32x4* w4 = (const f32x4*)(Wr + (size_t)i * E);
    f32x4 a = w4[0], b = w4[1];
    acc[0] += hv * a.x; acc[1] += hv * a.y; acc[2] += hv * a.z; acc[3] += hv * a.w;
    acc[4] += hv * b.x; acc[5] += hv * b.y; acc[6] += hv * b.z; acc[7] += hv * b.w;
  }
#pragma unroll
  for (int off = 32; off; off >>= 1)
#pragma unroll
    for (int e = 0; e < 8; e++) acc[e] += __shfl_xor(acc[e], off);
  if (lane == 0) {
    float lg[8], m = -3e38f;
#pragma unroll
    for (int e = 0; e < 8; e++) { lg[e] = acc[e] + br[e]; m = fmaxf(m, lg[e]); }
    float sum = 0.f;
#pragma unroll
    for (int e = 0; e < 8; e++) { lg[e] = expf(lg[e] - m); sum += lg[e]; }
    float inv = 1.f / sum;
#pragma unroll
    for (int e = 0; e < 8; e++) lg[e] *= inv;
    int i1 = 0;
#pragma unroll
    for (int e = 1; e < 8; e++) if (lg[e] > lg[i1]) i1 = e;
    int i2 = (i1 == 0) ? 1 : 0;
#pragma unroll
    for (int e = 0; e < 8; e++) if (e != i1 && lg[e] > lg[i2]) i2 = e;
    float p1 = lg[i1], p2 = lg[i2];
    float ws = p1 + p2 + 1e-9f;
    sel_e[tok * 2] = i1; sel_e[tok * 2 + 1] = i2;
    sel_w[tok * 2] = p1 / ws; sel_w[tok * 2 + 1] = p2 / ws;
    atomicAdd(counts + i1, 1);
    atomicAdd(counts + i2, 1);
  }
}

__global__ void k_offsets(const int* __restrict__ counts, int* __restrict__ offs) {
  if (threadIdx.x == 0) {
    int a = 0;
    for (int e = 0; e < E; e++) { offs[e] = a; a += counts[e]; }
    offs[E] = a;
  }
}

__global__ void k_scatter(const int* __restrict__ sel_e, const int* __restrict__ offs,
                          int* __restrict__ cursor, int* __restrict__ tok_list,
                          int* __restrict__ slot_of) {
  int tok = blockIdx.x * blockDim.x + threadIdx.x;
  if (tok >= NTOK) return;
  for (int k = 0; k < 2; k++) {
    int e = sel_e[tok * 2 + k];
    int pos = atomicAdd(cursor + e, 1);
    int g = offs[e] + pos;
    tok_list[g] = tok;
    slot_of[tok * 2 + k] = g;
  }
}

__global__ void k_combine(const float* __restrict__ oe, const float* __restrict__ sel_w,
                          const int* __restrict__ slot_of, float* __restrict__ x) {
  int idx = blockIdx.x * blockDim.x + threadIdx.x;  // NTOK*(H/4)
  if (idx >= NTOK * (H / 4)) return;
  int tok = idx / (H / 4), c4 = idx % (H / 4);
  float w0 = sel_w[tok * 2], w1 = sel_w[tok * 2 + 1];
  int s0 = slot_of[tok * 2], s1 = slot_of[tok * 2 + 1];
  f32x4 a = ((const f32x4*)(oe + (size_t)s0 * H))[c4];
  f32x4 b = ((const f32x4*)(oe + (size_t)s1 * H))[c4];
  f32x4* xp = (f32x4*)(x + (size_t)tok * H) + c4;
  *xp = *xp + w0 * a + w1 * b;
}

// ---------------- f32 SGEMM (64x64 tile, 4x4 micro, K-step 16) ----------------
// C[z][m][n] = sum_k A[z][row(m)][k] * B[z][k][n]    (all f32)
// Assumes N % 64 == 0 and K % 16 == 0 (true for all call sites).
// MODE 0: +bias(opt)  1: res+acc+bias  2: acc*alpha + causal  4: gelu(acc+bias)
template <int MODE, bool GATHER>
__global__ __launch_bounds__(256, 4) void k_sgemm(
    const float* __restrict__ A, long sAz, int lda,
    const float* __restrict__ B, long sBz, int ldb,
    float* __restrict__ C, int zdiv, long sChi, long sClo, int ldc,
    const float* __restrict__ bias, long sBias, const float* __restrict__ res,
    int M, int N, int K,
    const int* __restrict__ cnts, const int* __restrict__ offs,
    const int* __restrict__ gidx, float alpha) {
  const int z = blockIdx.z;
  const int Meff = cnts ? cnts[z] : M;
  const int tm = blockIdx.y;
  if (tm * 64 >= Meff) return;
  const int tn = blockIdx.x;
  const int row_base = offs ? offs[z] : 0;

  __shared__ float As[16][64];
  __shared__ float Bs[16][68];

  const int tid = threadIdx.x;

  // A staging: t -> row tm*64 + (t>>2), k-quad (t&3)*4
  int arow = tm * 64 + (tid >> 2);
  if (arow > Meff - 1) arow = Meff - 1;
  int agr = row_base + arow;
  if (GATHER) agr = gidx[agr];
  const int am = tid >> 2, ak = (tid & 3) * 4;
  const float* aP = A + (size_t)z * sAz + (size_t)agr * lda + ak;

  // B staging: t -> k-row t>>4, col-quad (t&15)*4
  const int bk = tid >> 4, bn4 = (tid & 15) * 4;
  const float* bP = B + (size_t)z * sBz + (size_t)bk * ldb + tn * 64 + bn4;

  float acc[4][4] = {};
  const int ty = tid >> 4, tx = tid & 15;

  for (int k0 = 0; k0 < K; k0 += 16) {
    float4 av = *(const float4*)aP;
    float4 bv = *(const float4*)bP;
    __syncthreads();
    As[ak + 0][am] = av.x; As[ak + 1][am] = av.y;
    As[ak + 2][am] = av.z; As[ak + 3][am] = av.w;
    *(float4*)&Bs[bk][bn4] = bv;
    __syncthreads();
#pragma unroll
    for (int kk = 0; kk < 16; ++kk) {
      float4 a4 = *(const float4*)&As[kk][ty * 4];
      float4 b4 = *(const float4*)&Bs[kk][tx * 4];
      float av_[4] = {a4.x, a4.y, a4.z, a4.w};
      float bv_[4] = {b4.x, b4.y, b4.z, b4.w};
#pragma unroll
      for (int i = 0; i < 4; ++i)
#pragma unroll
        for (int j = 0; j < 4; ++j) acc[i][j] = fmaf(av_[i], bv_[j], acc[i][j]);
    }
    aP += 16;
    bP += (size_t)16 * ldb;
  }

  const long out_off = (long)(z / zdiv) * sChi + (long)(z % zdiv) * sClo;
  const float* bz = bias ? bias + (size_t)z * sBias : nullptr;
  const int gc0 = tn * 64 + tx * 4;
  float4 b4v = {0.f, 0.f, 0.f, 0.f};
  if (MODE == 0 || MODE == 1 || MODE == 4) {
    if (bz) b4v = *(const float4*)&bz[gc0];
  }
#pragma unroll
  for (int i = 0; i < 4; ++i) {
    const int lrow = tm * 64 + ty * 4 + i;
    if (lrow >= Meff) continue;
    const long orow = row_base + lrow;
    const long idx = out_off + orow * (long)ldc + gc0;
    float4 v4;
    float* vp = (float*)&v4;
    const float* ap = (const float*)&acc[i][0];
    if (MODE == 0) {
      v4.x = acc[i][0] + b4v.x; v4.y = acc[i][1] + b4v.y;
      v4.z = acc[i][2] + b4v.z; v4.w = acc[i][3] + b4v.w;
    } else if (MODE == 1) {
      float4 r4 = *(const float4*)&res[idx];
      v4.x = r4.x + acc[i][0] + b4v.x; v4.y = r4.y + acc[i][1] + b4v.y;
      v4.z = r4.z + acc[i][2] + b4v.z; v4.w = r4.w + acc[i][3] + b4v.w;
    } else if (MODE == 2) {
#pragma unroll
      for (int j = 0; j < 4; ++j)
        vp[j] = ap[j] * alpha + ((gc0 + j > lrow) ? -1e9f : 0.f);
    } else if (MODE == 4) {
      const float* bp = (const float*)&b4v;
#pragma unroll
      for (int j = 0; j < 4; ++j) {
        float g = ap[j] + bp[j];
        vp[j] = 0.5f * g * (1.f + erff(g * 0.70710678118f));
      }
    }
    *(float4*)&C[idx] = v4;
  }
}

template <int MODE, bool GATHER>
static void sgemm(hipStream_t st, const float* A, long sAz, int lda, const float* B, long sBz,
                  int ldb, float* C, int zdiv, long sChi, long sClo, int ldc, const float* bias,
                  long sBias, const float* res, int M, int N, int K, int nz, const int* cnts,
                  const int* offs_, const int* gat, float alpha) {
  dim3 g(N / 64, (M + 63) / 64, nz);
  k_sgemm<MODE, GATHER><<<g, 256, 0, st>>>(A, sAz, lda, B, sBz, ldb, C, zdiv, sChi, sClo, ldc,
                                           bias, sBias, res, M, N, K, cnts, offs_, gat, alpha);
}

// ---------------- bf16 MFMA GEMM ----------------
// C[z][m][n] = sum_k A[z][row(m)][k] * Bt[z][n][k]   (A,Bt bf16; acc f32)
// MODE 0: f32 out (+bias opt)   4: bf16 out = gelu(acc + bias)
template <int MODE, bool GATHER>
__global__ __launch_bounds__(256, 2) void k_bgemm(
    const short* __restrict__ A, long sAz, int lda,
    const short* __restrict__ Bt, long sBz, int ldb,
    void* __restrict__ Cp, int zdiv, long sChi, long sClo, int ldc,
    const float* __restrict__ bias, long sBias,
    int M, int N, int K,
    const int* __restrict__ d_counts, const int* __restrict__ d_offs,
    const int* __restrict__ gidx) {
  const int z = blockIdx.z;
  const int Meff = d_counts ? d_counts[z] : M;
  const int tm = blockIdx.y;
  if (tm * 128 >= Meff) return;
  const int tn = blockIdx.x;
  const int row_base = d_offs ? d_offs[z] : 0;

  __shared__ short Abuf[128 * 32];
  __shared__ short Bbuf[128 * 32];

  const int tid = threadIdx.x;
  const int lane = tid & 63;
  const int w = tid >> 6;

  const short* Az = A + (size_t)z * sAz;
  const short* Bz = Bt + (size_t)z * sBz;

  const short* aSrc[2];
  const short* bSrc[2];
#pragma unroll
  for (int i = 0; i < 2; ++i) {
    const int srow = i * 64 + (tid >> 2);
    const int kb = (tid & 3) ^ (srow & 3);  // XOR swizzle (both-sides involution)
    int lrow = tm * 128 + srow;
    if (lrow > Meff - 1) lrow = Meff - 1;
    int ar = row_base + lrow;
    if (GATHER) ar = gidx[ar];
    aSrc[i] = Az + (size_t)ar * lda + kb * 8;
    int bcol = tn * 128 + srow;
    if (bcol > N - 1) bcol = N - 1;
    bSrc[i] = Bz + (size_t)bcol * ldb + kb * 8;
  }

  f32x4 acc[4][4];
#pragma unroll
  for (int a = 0; a < 4; ++a)
#pragma unroll
    for (int b = 0; b < 4; ++b) acc[a][b] = {0.f, 0.f, 0.f, 0.f};

  const int wr = (w >> 1) * 64;
  const int wc = (w & 1) * 64;
  const int r16 = lane & 15;
  const int kb4 = lane >> 4;
  const int swz = (kb4 ^ (r16 & 3)) * 8;
  int aoff[4], boff[4];
#pragma unroll
  for (int i = 0; i < 4; ++i) {
    aoff[i] = (wr + i * 16 + r16) * 32 + swz;
    boff[i] = (wc + i * 16 + r16) * 32 + swz;
  }
  char* const ldsA0 = (char*)Abuf + w * 1024;
  char* const ldsA1 = (char*)Abuf + 4096 + w * 1024;
  char* const ldsB0 = (char*)Bbuf + w * 1024;
  char* const ldsB1 = (char*)Bbuf + 4096 + w * 1024;

  for (int k0 = 0; k0 < K; k0 += 32) {
    gload16(aSrc[0], ldsA0);
    gload16(aSrc[1], ldsA1);
    gload16(bSrc[0], ldsB0);
    gload16(bSrc[1], ldsB1);
    aSrc[0] += 32; aSrc[1] += 32; bSrc[0] += 32; bSrc[1] += 32;
    __syncthreads();
    s16x8 af[4], bf[4];
#pragma unroll
    for (int i = 0; i < 4; ++i) {
      af[i] = *(const s16x8*)(Abuf + aoff[i]);
      bf[i] = *(const s16x8*)(Bbuf + boff[i]);
    }
#pragma unroll
    for (int mi = 0; mi < 4; ++mi)
#pragma unroll
      for (int ni = 0; ni < 4; ++ni)
        acc[mi][ni] =
            __builtin_amdgcn_mfma_f32_16x16x32_bf16(af[mi], bf[ni], acc[mi][ni], 0, 0, 0);
    __syncthreads();
  }

  const long out_off = (long)(z / zdiv) * sChi + (long)(z % zdiv) * sClo;
  const float* bz = bias ? (bias + (size_t)z * sBias) : nullptr;
  const int q4 = lane >> 4;
#pragma unroll
  for (int ni = 0; ni < 4; ++ni) {
    const int gcol = tn * 128 + wc + ni * 16 + r16;
    if (gcol >= N) continue;
    const float bv = bz ? bz[gcol] : 0.f;
#pragma unroll
    for (int mi = 0; mi < 4; ++mi) {
#pragma unroll
      for (int j = 0; j < 4; ++j) {
        const int lrow = tm * 128 + wr + mi * 16 + q4 * 4 + j;
        if (lrow >= Meff) continue;
        const long orow = row_base + lrow;
        const long idx = out_off + orow * (long)ldc + gcol;
        const float v = acc[mi][ni][j];
        if (MODE == 0) {
          ((float*)Cp)[idx] = v + bv;
        } else if (MODE == 4) {
          float g = v + bv;
          g = 0.5f * g * (1.f + erff(g * 0.70710678118f));
          ((short*)Cp)[idx] = f2bf(g);
        }
      }
    }
  }
}

template <int MODE, bool GATHER>
static void bgemm(hipStream_t st, const short* A, long sAz, int lda, const short* Bt, long sBz,
                  int ldb, void* C, int zdiv, long sChi, long sClo, int ldc, const float* bias,
                  long sBias, int M, int N, int K, int nz, const int* cnts, const int* offs_,
                  const int* gat) {
  dim3 g((N + 127) / 128, (M + 127) / 128, nz);
  k_bgemm<MODE, GATHER><<<g, 256, 0, st>>>(A, sAz, lda, Bt, sBz, ldb, C, zdiv, sChi, sClo, ldc,
                                           bias, sBias, M, N, K, cnts, offs_, gat);
}

// ---------------- launch ----------------
extern "C" void kernel_launch(void* const* d_in, const int* in_sizes, int n_in, void* d_out,
                              int out_size, void* d_ws, size_t ws_size, hipStream_t stream) {
  (void)in_sizes; (void)n_in; (void)out_size; (void)ws_size;
  const int*   ids  = (const int*)d_in[0];
  const float* emb  = (const float*)d_in[1];
  const float* ln1w = (const float*)d_in[2];
  const float* ln1b = (const float*)d_in[3];
  const float* ln2w = (const float*)d_in[4];
  const float* ln2b = (const float*)d_in[5];
  const float* lnfw = (const float*)d_in[6];
  const float* lnfb = (const float*)d_in[7];
  const float* Wq = (const float*)d_in[8];
  const float* bq = (const float*)d_in[9];
  const float* Wk = (const float*)d_in[10];
  const float* bk = (const float*)d_in[11];
  const float* Wv = (const float*)d_in[12];
  const float* bv = (const float*)d_in[13];
  const float* Wo = (const float*)d_in[14];
  const float* bo = (const float*)d_in[15];
  const float* Wr = (const float*)d_in[16];
  const float* br = (const float*)d_in[17];
  const float* W1 = (const float*)d_in[18];
  const float* b1 = (const float*)d_in[19];
  const float* W2 = (const float*)d_in[20];
  const float* b2 = (const float*)d_in[21];
  float* out = (float*)d_out;

  char* p = (char*)d_ws;
  auto alloc = [&](size_t bytes) {
    char* r = p;
    p += (bytes + 255) & ~(size_t)255;
    return r;
  };
  short* embB = (short*)alloc((size_t)V * H * 2);          // 77.2 MB
  short* W1T  = (short*)alloc((size_t)E * F * H * 2);      // 37.7 MB (layer 1, [E][F][H])
  short* W2T  = (short*)alloc((size_t)E * H * F * 2);      // 37.7 MB (layer 1, [E][H][F])
  float* bqkv = (float*)alloc((size_t)L * 3 * H * 4);
  float* Wcat = (float*)alloc((size_t)3 * H * H * 4);      // 7.1 MB (per-layer reuse)
  float* cosT = (float*)alloc((size_t)S * 32 * 4);
  float* sinT = (float*)alloc((size_t)S * 32 * 4);
  float* x    = (float*)alloc((size_t)NTOK * H * 4);
  float* hbuf = (float*)alloc((size_t)NTOK * H * 4);
  float* qf   = (float*)alloc((size_t)NTOK * H * 4);
  float* kT   = (float*)alloc((size_t)NTOK * H * 4);
  float* vf   = (float*)alloc((size_t)NTOK * H * 4);
  float* o    = (float*)alloc((size_t)NTOK * H * 4);
  short* xb   = (short*)alloc((size_t)NTOK * H * 2);
  short* xb2  = (short*)alloc((size_t)NTOK * H * 2);
  // union region: qkvl (18.9MB) | att f32 (100.7MB) | act f32 (50.3) / act bf16 (25.2) + oe
  char* uni = alloc((size_t)Bb * NHd * S * S * 4);         // 100.7 MB
  float* qkvl  = (float*)uni;
  float* att   = (float*)uni;
  float* act_f = (float*)uni;
  short* act_b = (short*)uni;
  float* oe    = (float*)(uni + (size_t)NSLOT * F * 4);
  int* counts  = (int*)alloc(2 * E * 4);
  int* cursor  = counts + E;
  int* offs    = (int*)alloc((E + 1) * 4);
  int* sel_e   = (int*)alloc((size_t)NTOK * 2 * 4);
  float* sel_w = (float*)alloc((size_t)NTOK * 2 * 4);
  int* slot_of = (int*)alloc((size_t)NTOK * 2 * 4);
  int* tok_lst = (int*)alloc((size_t)NSLOT * 4);

  // ---- prologue ----
  long nEmb4 = (long)V * H / 4;
  k_f32_to_bf16<<<(nEmb4 + 255) / 256, 256, 0, stream>>>(emb, embB, nEmb4);
  k_bqkv<<<(L * 3 * H + 255) / 256, 256, 0, stream>>>(bq, bk, bv, bqkv);
  k_ropetab<<<(S * 32 + 255) / 256, 256, 0, stream>>>(cosT, sinT);
  k_embed<<<(NTOK * (H / 4) + 255) / 256, 256, 0, stream>>>(ids, emb, x);
  // layer-1 expert weights -> transposed bf16 (downstream of all routers)
  dim3 tb(32, 8);
  k_transpose_bf16<<<dim3(F / 32, H / 32, E), tb, 0, stream>>>(
      W1 + (size_t)1 * E * H * F, W1T, H, F, (long)H * F, (long)F * H);
  k_transpose_bf16<<<dim3(H / 32, F / 32, E), tb, 0, stream>>>(
      W2 + (size_t)1 * E * F * H, W2T, F, H, (long)F * H, (long)H * F);

  for (int l = 0; l < L; l++) {
    // --- attention (f32; upstream of routers) ---
    k_layernorm<false><<<NTOK / 4, 256, 0, stream>>>(x, ln1w + l * H, ln1b + l * H, hbuf);
    k_wcat<<<(H * H + 255) / 256, 256, 0, stream>>>(Wq + (size_t)l * H * H,
                                                    Wk + (size_t)l * H * H,
                                                    Wv + (size_t)l * H * H, Wcat);
    sgemm<0, false>(stream, hbuf, 0, H, Wcat, 0, 3 * H, qkvl, 1, 0, 0, 3 * H,
                    bqkv + l * 3 * H, 0, nullptr, NTOK, 3 * H, H, 1, nullptr, nullptr, nullptr,
                    1.f);
    k_rope<<<(Bb * S * NHd * 32 + 255) / 256, 256, 0, stream>>>(qkvl, cosT, sinT, qf, kT, vf);
    sgemm<2, false>(stream, qf, (long)S * HD, HD, kT, (long)HD * S, S, att, 1, (long)S * S, 0,
                    S, nullptr, 0, nullptr, S, S, HD, Bb * NHd, nullptr, nullptr, nullptr,
                    0.125f);
    k_softmax<<<(Bb * NHd * S) / 4, 256, 0, stream>>>(att);
    sgemm<0, false>(stream, att, (long)S * S, S, vf, (long)S * HD, HD, o, NHd, (long)S * H, HD,
                    H, nullptr, 0, nullptr, S, HD, S, Bb * NHd, nullptr, nullptr, nullptr, 1.f);
    sgemm<1, false>(stream, o, 0, H, Wo + (size_t)l * H * H, 0, H, x, 1, 0, 0, H, bo + l * H, 0,
                    x, NTOK, H, H, 1, nullptr, nullptr, nullptr, 1.f);

    // --- MoE ---
    k_layernorm<false><<<NTOK / 4, 256, 0, stream>>>(x, ln2w + l * H, ln2b + l * H, hbuf);
    hipMemsetAsync(counts, 0, 2 * E * sizeof(int), stream);
    k_router<<<NTOK / 4, 256, 0, stream>>>(hbuf, Wr + (size_t)l * H * E, br + l * E, sel_w,
                                           sel_e, counts);
    k_offsets<<<1, 64, 0, stream>>>(counts, offs);
    k_scatter<<<(NTOK + 255) / 256, 256, 0, stream>>>(sel_e, offs, cursor, tok_lst, slot_of);
    if (l == 0) {
      // upstream of router 1: experts in f32
      sgemm<4, true>(stream, hbuf, 0, H, W1 + (size_t)l * E * H * F, (long)H * F, F, act_f, 1,
                     0, 0, F, b1 + (size_t)l * E * F, F, nullptr, NSLOT, F, H, E, counts, offs,
                     tok_lst, 1.f);
      sgemm<0, false>(stream, act_f, 0, F, W2 + (size_t)l * E * F * H, (long)F * H, H, oe, 1, 0,
                      0, H, b2 + (size_t)l * E * H, H, nullptr, NSLOT, H, F, E, counts, offs,
                      nullptr, 1.f);
    } else {
      // downstream of all routers: bf16 MFMA experts
      k_f32_to_bf16<<<(NTOK * H / 4 + 255) / 256, 256, 0, stream>>>(hbuf, xb2,
                                                                    (long)NTOK * H / 4);
      bgemm<4, true>(stream, xb2, 0, H, W1T, (long)F * H, H, act_b, 1, 0, 0, F,
                     b1 + (size_t)l * E * F, F, NSLOT, F, H, E, counts, offs, tok_lst);
      bgemm<0, false>(stream, act_b, 0, F, W2T, (long)H * F, F, oe, 1, 0, 0, H,
                      b2 + (size_t)l * E * H, H, NSLOT, H, F, E, counts, offs, nullptr);
    }
    k_combine<<<(NTOK * (H / 4) + 255) / 256, 256, 0, stream>>>(oe, sel_w, slot_of, x);
  }

  // --- final LN + tied logits (bf16 MFMA; downstream of all routers) ---
  k_layernorm<true><<<NTOK / 4, 256, 0, stream>>>(x, lnfw, lnfb, xb);
  bgemm<0, false>(stream, xb, 0, H, embB, 0, H, out, 1, 0, 0, V, nullptr, 0, NTOK, V, H, 1,
                  nullptr, nullptr, nullptr);
}